// Round 11
// baseline (286.716 us; speedup 1.0000x reference)
//
#include <hip/hip_runtime.h>
#include <math.h>

#define NN 512     // N_NODES
#define SD 32      // STATE_DIM == MESSAGE_DIM
#define HM 64      // H_MSG
#define NB 256     // blocks
#define NGRP 16    // barrier tree groups

typedef _Float16 f16x8 __attribute__((ext_vector_type(8)));
typedef float floatx4 __attribute__((ext_vector_type(4)));
typedef unsigned uintx4 __attribute__((ext_vector_type(4)));

// ---- dynamic LDS layout (bytes) ----
#define OFF_HBS   0        // 512 rows x 144 B (packed f16 h-projections) = 73728
#define OFF_M2L   73728    // 16 waves x (16 edges x 144 B packed-f16 m2) = 36864
#define OFF_MSUM  110592   // 16x32 f32 = 2048
#define OFF_HJP   112640   // 2x64 f32
#define OFF_H     113152   // 2x32 f32
#define OFF_MSG   113408   // 2x32 f32
#define OFF_GI    113664   // 2x96 f32
#define OFF_GH    114432   // 2x96 f32
#define LDS_TOTAL 115200

struct KParams {
    const float *J, *b, *mpW1, *mpb1, *mpW2, *mpb2, *mpW3, *mpb3;
    const float *Wih, *Whh, *bih, *bhh;
    const float *rW1, *rb1, *rW2, *rb2, *rW3, *rb3;
    float *out;
    unsigned *hb0, *hb1;   // hip double buffers, packed f16 pairs (512*32 u32)
    unsigned *bar;         // tree barrier state
};

__device__ __forceinline__ float sigmoidf_(float x) {
    return 1.0f / (1.0f + __expf(-x));
}

// ---- packed f16 ops as raw VOP3P (ROCm header-independent) ----------------
__device__ __forceinline__ unsigned pkrtz(float a, float b) {
    unsigned r;
    asm("v_cvt_pkrtz_f16_f32 %0, %1, %2" : "=v"(r) : "v"(a), "v"(b));
    return r;
}
__device__ __forceinline__ unsigned pk_add(unsigned a, unsigned b) {
    unsigned r;
    asm("v_pk_add_f16 %0, %1, %2" : "=v"(r) : "v"(a), "v"(b));
    return r;
}
__device__ __forceinline__ unsigned pk_fma(unsigned a, unsigned b, unsigned c) {
    unsigned r;
    asm("v_pk_fma_f16 %0, %1, %2, %3" : "=v"(r) : "v"(a), "v"(b), "v"(c));
    return r;
}
__device__ __forceinline__ unsigned pk_relu(unsigned a) {
    unsigned r, z = 0u;
    asm("v_pk_max_f16 %0, %1, %2" : "=v"(r) : "v"(a), "v"(z));
    return r;
}

// ---- coherence-point primitives (no cache maintenance anywhere) -----------
__device__ __forceinline__ unsigned ld_bypass_u32(const unsigned* p) {
    unsigned r;
    asm volatile("global_load_dword %0, %1, off sc0 sc1\n\ts_waitcnt vmcnt(0)"
                 : "=v"(r) : "v"(p) : "memory");
    return r;
}
__device__ __forceinline__ void issue16(const unsigned* p, uintx4& d) {
    asm volatile("global_load_dwordx4 %0, %1, off sc0 sc1" : "=&v"(d) : "v"(p));
}
__device__ __forceinline__ void waitall4(uintx4& a, uintx4& b, uintx4& c, uintx4& d) {
    asm volatile("s_waitcnt vmcnt(0)"
                 : "+v"(a), "+v"(b), "+v"(c), "+v"(d) :: "memory");
}

// Tree sense barrier (monotonic rounds, 1-based).
__device__ __forceinline__ void xbarrier(unsigned* bar, unsigned round, int bid) {
    __syncthreads();
    if (threadIdx.x == 0) {
        unsigned g = (unsigned)bid >> 4;
        unsigned old = atomicAdd(&bar[g * 16], 1u);
        if (old + 1u == round * NGRP) {
            unsigned r2 = atomicAdd(&bar[256], 1u);
            if (r2 + 1u == round * NGRP) {
                atomicMax(&bar[272], round);
            } else {
                while (ld_bypass_u32(&bar[272]) < round) __builtin_amdgcn_s_sleep(2);
            }
        } else {
            while (ld_bypass_u32(&bar[272]) < round) __builtin_amdgcn_s_sleep(2);
        }
    }
    __syncthreads();
}

// 256 blocks x 1024 threads, 4 waves/SIMD. __launch_bounds__(1024, 4):
// min 4 waves/EU -> VGPR budget 128 (the same count the identical per-thread
// code compiled to at 512 threads in R9, spill-free). R10's (1024) default
// targeted 64 VGPR -> massive scratch spills (288 MB FETCH / 185 MB WRITE).
// Block owns nodes 2*bid, 2*bid+1 (waves 0-7 / 8-15; each wave 4 groups of
// 16 source rows). Swapped-operand MFMA edge MLP, packed f16, per-wave
// in-order LDS transpose, stage-all-then-sync staging.
__global__ __launch_bounds__(1024, 4) void fused_kernel(KParams p)
{
    extern __shared__ __align__(16) char smem[];
    char* hbS   = smem + OFF_HBS;                  // packed f16 rows, stride 144 B
    float (*msum)[32] = (float(*)[32])(smem + OFF_MSUM);
    float (*hjpS)[64] = (float(*)[64])(smem + OFF_HJP);
    float (*hS)[32]   = (float(*)[32])(smem + OFF_H);
    float (*msgS)[32] = (float(*)[32])(smem + OFF_MSG);
    float (*giS)[96]  = (float(*)[96])(smem + OFF_GI);
    float (*ghS)[96]  = (float(*)[96])(smem + OFF_GH);

    const int tid  = threadIdx.x;
    const int lane = tid & 63;
    const int wave = tid >> 6;       // 0..15
    const int nsel = wave >> 3;      // node select
    const int nw   = wave & 7;       // wave-within-node (0..7)
    const int j    = blockIdx.x * 2 + nsel;
    const int q    = lane >> 4;
    const int c    = lane & 15;

    char* m2Lw = smem + OFF_M2L + wave * 2304;     // per-wave 16 edges x 144 B

    // ---------------- prep: h==0 projections, packed f16 -> LLC -----------
    if (tid < 128) {
        int node = tid >> 6, cc = tid & 63;
        int jj = blockIdx.x * 2 + node;
        const float* wr = p.mpW1 + cc * 67;
        float bj = p.b[jj];
        hjpS[node][cc] = bj * wr[66] + p.mpb1[cc];
        float si = bj * wr[65];
        float sp = __shfl(si, lane ^ 1);
        if (!(lane & 1))
            atomicExch(&p.hb0[jj * 32 + (cc >> 1)], pkrtz(si, sp));
    }

    // ---------------- persistent per-lane preloads ----------------
    unsigned wj2a[4], wj2b[4];
    #pragma unroll
    for (int i = 0; i < 4; ++i) {
        wj2a[i] = pkrtz(p.mpW1[(q * 8 + 2 * i) * 67 + 64],
                        p.mpW1[(q * 8 + 2 * i + 1) * 67 + 64]);
        wj2b[i] = pkrtz(p.mpW1[(q * 8 + 2 * i + 32) * 67 + 64],
                        p.mpW1[(q * 8 + 2 * i + 33) * 67 + 64]);
    }
    floatx4 b2i[4], b3i[2];
    #pragma unroll
    for (int t4 = 0; t4 < 4; ++t4)
        #pragma unroll
        for (int r = 0; r < 4; ++r) b2i[t4][r] = p.mpb2[t4 * 16 + q * 4 + r];
    #pragma unroll
    for (int t2 = 0; t2 < 2; ++t2)
        #pragma unroll
        for (int r = 0; r < 4; ++r) b3i[t2][r] = p.mpb3[t2 * 16 + q * 4 + r];

    // A-operand weight fragments: Aw2[f][t4][s] = W2[t4*16+c][f*32+q*8+s]
    f16x8 Aw2[2][4], Aw3[2][2];
    #pragma unroll
    for (int f = 0; f < 2; ++f)
        #pragma unroll
        for (int t4 = 0; t4 < 4; ++t4) {
            const float* src = p.mpW2 + (t4 * 16 + c) * 64 + f * 32 + q * 8;
            #pragma unroll
            for (int s = 0; s < 8; ++s) Aw2[f][t4][s] = (_Float16)src[s];
        }
    #pragma unroll
    for (int f = 0; f < 2; ++f)
        #pragma unroll
        for (int t2 = 0; t2 < 2; ++t2) {
            const float* src = p.mpW3 + (t2 * 16 + c) * 64 + f * 32 + q * 8;
            #pragma unroll
            for (int s = 0; s < 8; ++s) Aw3[f][t2][s] = (_Float16)src[s];
        }

    // J values: wave nw handles groups {8k+nw}, k=0..3; lane (k,c) -> row
    const float jA = p.J[((8 * (lane >> 4) + nw) * 16 + (lane & 15)) * NN + j];

    xbarrier(p.bar, 1, blockIdx.x);    // hb0 visible everywhere

    // ---------------- 5 message-passing steps ----------------
    for (int t = 0; t < 5; ++t) {
        const unsigned* hb_read = (t & 1) ? p.hb1 : p.hb0;
        unsigned*       hb_next = (t & 1) ? p.hb0 : p.hb1;

        // per-step hjp packed pairs
        unsigned hjp2a[4], hjp2b[4];
        #pragma unroll
        for (int i = 0; i < 4; ++i) {
            hjp2a[i] = pkrtz(hjpS[nsel][q * 8 + 2 * i], hjpS[nsel][q * 8 + 2 * i + 1]);
            hjp2b[i] = pkrtz(hjpS[nsel][q * 8 + 2 * i + 32], hjpS[nsel][q * 8 + 2 * i + 33]);
        }

        float accf[2][4];
        #pragma unroll
        for (int t2 = 0; t2 < 2; ++t2)
            #pragma unroll
            for (int r = 0; r < 4; ++r) accf[t2][r] = 0.0f;

        // ---- staging: 64 KB hb -> LDS, 64 B/thread, one sync ----
        {
            uintx4 cr[4];
            const unsigned* gp = hb_read + tid * 4;   // 16 B per chunk per thread
            #pragma unroll
            for (int k = 0; k < 4; ++k) issue16(gp + k * 4096, cr[k]);
            waitall4(cr[0], cr[1], cr[2], cr[3]);
            #pragma unroll
            for (int k = 0; k < 4; ++k) {
                int row = k * 128 + (tid >> 3);
                *(uintx4*)(hbS + row * 144 + (tid & 7) * 16) = cr[k];
            }
        }
        __syncthreads();

        // ---- edge phase: 4 groups per wave, swapped MFMA, packed f16 ----
        auto edge_group = [&](int G, float Jv) {
            const char* rb = hbS + (G * 16 + c) * 144;
            uintx4 vlo = *(const uintx4*)(rb + q * 16);
            uintx4 vhi = *(const uintx4*)(rb + 64 + q * 16);
            const unsigned Jp = pkrtz(Jv, Jv);

            uintx4 a0u, a1u;
            #pragma unroll
            for (int i = 0; i < 4; ++i) {
                a0u[i] = pk_relu(pk_fma(Jp, wj2a[i], pk_add(vlo[i], hjp2a[i])));
                a1u[i] = pk_relu(pk_fma(Jp, wj2b[i], pk_add(vhi[i], hjp2b[i])));
            }
            f16x8 B0 = __builtin_bit_cast(f16x8, a0u);
            f16x8 B1 = __builtin_bit_cast(f16x8, a1u);

            // GEMM1 (swapped): c1[t4] lane(q,c): outch=t4*16+q*4+r, edge=c
            floatx4 c1[4];
            #pragma unroll
            for (int t4 = 0; t4 < 4; ++t4) {
                c1[t4] = __builtin_amdgcn_mfma_f32_16x16x32_f16(Aw2[0][t4], B0, b2i[t4], 0, 0, 0);
                c1[t4] = __builtin_amdgcn_mfma_f32_16x16x32_f16(Aw2[1][t4], B1, c1[t4], 0, 0, 0);
            }
            // relu + pack adjacent outch pairs (in-lane) -> 4 ds_write_b64
            #pragma unroll
            for (int t4 = 0; t4 < 4; ++t4) {
                unsigned p0 = pkrtz(fmaxf(c1[t4][0], 0.f), fmaxf(c1[t4][1], 0.f));
                unsigned p1 = pkrtz(fmaxf(c1[t4][2], 0.f), fmaxf(c1[t4][3], 0.f));
                *(uint2*)(m2Lw + c * 144 + t4 * 32 + q * 8) = make_uint2(p0, p1);
            }
            // B2-frags: packed f16 channels, 2 ds_read_b128 (same-wave in-order DS)
            uintx4 rlo = *(const uintx4*)(m2Lw + c * 144 + q * 16);
            uintx4 rhi = *(const uintx4*)(m2Lw + c * 144 + 64 + q * 16);
            f16x8 B2lo = __builtin_bit_cast(f16x8, rlo);
            f16x8 B2hi = __builtin_bit_cast(f16x8, rhi);

            // GEMM2 (swapped): c2[t2] lane(q,c): outch2=t2*16+q*4+r, edge=c
            floatx4 c2[2];
            #pragma unroll
            for (int t2 = 0; t2 < 2; ++t2) {
                c2[t2] = __builtin_amdgcn_mfma_f32_16x16x32_f16(Aw3[0][t2], B2lo, b3i[t2], 0, 0, 0);
                c2[t2] = __builtin_amdgcn_mfma_f32_16x16x32_f16(Aw3[1][t2], B2hi, c2[t2], 0, 0, 0);
            }
            #pragma unroll
            for (int t2 = 0; t2 < 2; ++t2)
                #pragma unroll
                for (int r = 0; r < 4; ++r)
                    accf[t2][r] += fmaxf(c2[t2][r], 0.0f);
        };

        #pragma unroll
        for (int k = 0; k < 4; ++k)
            edge_group(8 * k + nw, __shfl(jA, k * 16 + c));

        // column sums: butterfly over edge lanes c (xor 1,2,4,8 within quad)
        #pragma unroll
        for (int m = 1; m < 16; m <<= 1)
            #pragma unroll
            for (int t2 = 0; t2 < 2; ++t2)
                #pragma unroll
                for (int r = 0; r < 4; ++r)
                    accf[t2][r] += __shfl_xor(accf[t2][r], m);
        if (c == 0) {
            #pragma unroll
            for (int t2 = 0; t2 < 2; ++t2)
                #pragma unroll
                for (int r = 0; r < 4; ++r)
                    msum[wave][t2 * 16 + q * 4 + r] = accf[t2][r];
        }
        __syncthreads();

        // ---- block-local tail ----
        if (tid < 64) {
            int node = tid >> 5, d = tid & 31;
            float s = 0.0f;
            #pragma unroll
            for (int w = 0; w < 8; ++w) s += msum[node * 8 + w][d];
            msgS[node][d] = s;
        }
        __syncthreads();

        if (tid < 192) {
            int node = tid / 96, r = tid % 96;
            int g = r >> 5, d = r & 31;
            const float* wi = p.Wih + (g * 32 + d) * 64;
            float a  = p.bih[g * 32 + d];
            float bb = p.bhh[g * 32 + d];
            if (t > 0) {
                const float* wh = p.Whh + (g * 32 + d) * 32;
                #pragma unroll
                for (int k = 0; k < 32; ++k) {
                    float hv = hS[node][k];
                    a  = fmaf(hv, wi[k], a);
                    bb = fmaf(hv, wh[k], bb);
                }
            }
            #pragma unroll
            for (int k = 0; k < 32; ++k) a = fmaf(msgS[node][k], wi[32 + k], a);
            giS[node][r] = a; ghS[node][r] = bb;
        }
        __syncthreads();

        if (tid < 64) {
            int node = tid >> 5, d = tid & 31;
            float r  = sigmoidf_(giS[node][d] + ghS[node][d]);
            float z  = sigmoidf_(giS[node][32 + d] + ghS[node][32 + d]);
            float ng = tanhf(giS[node][64 + d] + r * ghS[node][64 + d]);
            float hold = (t > 0) ? hS[node][d] : 0.0f;
            hS[node][d] = (1.0f - z) * ng + z * hold;
        }
        __syncthreads();

        if (t < 4) {
            if (tid < 128) {   // projections for next step -> hjpS + LLC (packed f16)
                int node = tid >> 6, cc = tid & 63;
                int jj = blockIdx.x * 2 + node;
                const float* wr = p.mpW1 + cc * 67;
                float bj = p.b[jj];
                float si = bj * wr[65];
                float sj = bj * wr[66] + p.mpb1[cc];
                #pragma unroll
                for (int d = 0; d < 32; ++d) {
                    float hv = hS[node][d];
                    si = fmaf(hv, wr[d], si);
                    sj = fmaf(hv, wr[32 + d], sj);
                }
                hjpS[node][cc] = sj;
                float sp = __shfl(si, lane ^ 1);
                if (!(lane & 1))
                    atomicExch(&hb_next[jj * 32 + (cc >> 1)], pkrtz(si, sp));
            }
            xbarrier(p.bar, (unsigned)(t + 2), blockIdx.x);
        } else {
            if (wave < 2) {   // readout
                int node = wave;
                int jj = blockIdx.x * 2 + node;
                float y1 = p.rb1[lane];
                #pragma unroll
                for (int k = 0; k < 32; ++k) y1 = fmaf(hS[node][k], p.rW1[lane * 32 + k], y1);
                y1 = fmaxf(y1, 0.0f);
                float y2 = p.rb2[lane];
                #pragma unroll
                for (int k = 0; k < 64; ++k) y2 = fmaf(__shfl(y1, k), p.rW2[lane * 64 + k], y2);
                y2 = fmaxf(y2, 0.0f);
                float y3 = (lane < 2) ? p.rb3[lane] : 0.0f;
                #pragma unroll
                for (int k = 0; k < 64; ++k) {
                    float v = __shfl(y2, k);
                    if (lane < 2) y3 = fmaf(v, p.rW3[lane * 64 + k], y3);
                }
                if (lane < 2) p.out[jj * 2 + lane] = sigmoidf_(y3);
            }
        }
    }
}

// ---------------------------------------------------------------------------
extern "C" void kernel_launch(void* const* d_in, const int* in_sizes, int n_in,
                              void* d_out, int out_size, void* d_ws, size_t ws_size,
                              hipStream_t stream)
{
    float* ws = (float*)d_ws;

    KParams p;
    p.J    = (const float*)d_in[0];
    p.b    = (const float*)d_in[1];
    p.mpW1 = (const float*)d_in[2];
    p.mpb1 = (const float*)d_in[3];
    p.mpW2 = (const float*)d_in[4];
    p.mpb2 = (const float*)d_in[5];
    p.mpW3 = (const float*)d_in[6];
    p.mpb3 = (const float*)d_in[7];
    p.Wih  = (const float*)d_in[8];
    p.Whh  = (const float*)d_in[9];
    p.bih  = (const float*)d_in[10];
    p.bhh  = (const float*)d_in[11];
    p.rW1  = (const float*)d_in[12];
    p.rb1  = (const float*)d_in[13];
    p.rW2  = (const float*)d_in[14];
    p.rb2  = (const float*)d_in[15];
    p.rW3  = (const float*)d_in[16];
    p.rb3  = (const float*)d_in[17];
    p.out  = (float*)d_out;

    p.hb0  = (unsigned*)ws;            // 512*32 u32 (packed f16 pairs)
    p.hb1  = (unsigned*)(ws + 16384);
    p.bar  = (unsigned*)(ws + 32768);  // tree barrier state

    (void)hipMemsetAsync(p.bar, 0, 4096, stream);

    (void)hipFuncSetAttribute((const void*)fused_kernel,
                              hipFuncAttributeMaxDynamicSharedMemorySize, LDS_TOTAL);
    fused_kernel<<<dim3(NB), dim3(1024), LDS_TOTAL, stream>>>(p);
}

// Round 13
// 176.404 us; speedup vs baseline: 1.6253x; 1.6253x over previous
//
#include <hip/hip_runtime.h>
#include <math.h>

#define NN 512     // N_NODES
#define SD 32      // STATE_DIM == MESSAGE_DIM
#define HM 64      // H_MSG
#define NB 256     // blocks (2 nodes each; 1 block/CU, 2x residency slack)
#define NGRP 16    // barrier tree groups

typedef _Float16 f16x8 __attribute__((ext_vector_type(8)));
typedef float floatx4 __attribute__((ext_vector_type(4)));
typedef unsigned uintx4 __attribute__((ext_vector_type(4)));

// ---- dynamic LDS layout (bytes), total 114688 (1 block/CU) ----
#define OFF_HBS   0        // 256 rows x 144 B packed-f16 (one phase)  = 36864
#define OFF_M2L   36864    // 8 waves x 2304 B                         = 18432
#define OFF_WIH   55296    // f32 96x65 (pad +1)                       = 24960
#define OFF_WHH   80256    // f32 96x33 (pad +1)                       = 12672
#define OFF_BIH   92928    // 96 f32
#define OFF_BHH   93312    // 96 f32
#define OFF_B1    93696    // 64 f32 (mp_b1)
#define OFF_W1T   93952    // f32 67x64 (mpW1 transposed)              = 17152
#define OFF_MSUM  111104   // 8x32 f32
#define OFF_HJP   112128   // 2x64 f32
#define OFF_H     112640   // 2x32 f32
#define OFF_MSG   112896   // 2x32 f32
#define OFF_GI    113152   // 2x96 f32
#define OFF_GH    113920   // 2x96 f32
#define LDS_TOTAL 114688

struct KParams {
    const float *J, *b, *mpW1, *mpb1, *mpW2, *mpb2, *mpW3, *mpb3;
    const float *Wih, *Whh, *bih, *bhh;
    const float *rW1, *rb1, *rW2, *rb2, *rW3, *rb3;
    float *out;
    unsigned *hb0, *hb1;   // hip double buffers, packed f16 pairs (512*32 u32)
    unsigned *bar;         // tree barrier state
};

__device__ __forceinline__ float sigmoidf_(float x) {
    return 1.0f / (1.0f + __expf(-x));
}

// ---- packed f16 ops as raw VOP3P ----
__device__ __forceinline__ unsigned pkrtz(float a, float b) {
    unsigned r;
    asm("v_cvt_pkrtz_f16_f32 %0, %1, %2" : "=v"(r) : "v"(a), "v"(b));
    return r;
}
__device__ __forceinline__ unsigned pk_add(unsigned a, unsigned b) {
    unsigned r;
    asm("v_pk_add_f16 %0, %1, %2" : "=v"(r) : "v"(a), "v"(b));
    return r;
}
__device__ __forceinline__ unsigned pk_fma(unsigned a, unsigned b, unsigned c) {
    unsigned r;
    asm("v_pk_fma_f16 %0, %1, %2, %3" : "=v"(r) : "v"(a), "v"(b), "v"(c));
    return r;
}
__device__ __forceinline__ unsigned pk_relu(unsigned a) {
    unsigned r, z = 0u;
    asm("v_pk_max_f16 %0, %1, %2" : "=v"(r) : "v"(a), "v"(z));
    return r;
}

// ---- coherence-point primitives ----
__device__ __forceinline__ unsigned ld_bypass_u32(const unsigned* p) {
    unsigned r;
    asm volatile("global_load_dword %0, %1, off sc0 sc1\n\ts_waitcnt vmcnt(0)"
                 : "=v"(r) : "v"(p) : "memory");
    return r;
}
__device__ __forceinline__ void issue16(const unsigned* p, uintx4& d) {
    asm volatile("global_load_dwordx4 %0, %1, off sc0 sc1" : "=&v"(d) : "v"(p));
}
__device__ __forceinline__ void waitall4(uintx4& a, uintx4& b, uintx4& c, uintx4& d) {
    asm volatile("s_waitcnt vmcnt(0)"
                 : "+v"(a), "+v"(b), "+v"(c), "+v"(d) :: "memory");
}

// Tree sense barrier (monotonic rounds, 1-based), 16 groups of 16 blocks.
__device__ __forceinline__ void xbarrier(unsigned* bar, unsigned round, int bid) {
    __syncthreads();   // drains vmem (incl. atomicExch h-stores) before arrival
    if (threadIdx.x == 0) {
        unsigned g = (unsigned)bid >> 4;
        unsigned old = atomicAdd(&bar[g * 16], 1u);
        if (old + 1u == round * 16u) {
            unsigned r2 = atomicAdd(&bar[256], 1u);
            if (r2 + 1u == round * NGRP) {
                atomicMax(&bar[272], round);
            } else {
                while (ld_bypass_u32(&bar[272]) < round) __builtin_amdgcn_s_sleep(2);
            }
        } else {
            while (ld_bypass_u32(&bar[272]) < round) __builtin_amdgcn_s_sleep(2);
        }
    }
    __syncthreads();
}

// 256 blocks x 512 threads; block owns nodes 2*bid, 2*bid+1 (waves 0-3/4-7).
// R9 edge structure (swapped MFMA, packed f16, stride-144 LDS) + two-phase
// hb staging with cross-phase prefetch + ALL per-step tail weights in LDS
// (Wih/Whh/biases/W1T) to kill the 256-B-stride global gathers.
__global__ __launch_bounds__(512, 1) void fused_kernel(KParams p)
{
    extern __shared__ __align__(16) char smem[];
    char* hbS   = smem + OFF_HBS;                  // packed f16 rows, stride 144 B
    float* WihS = (float*)(smem + OFF_WIH);        // stride 65
    float* WhhS = (float*)(smem + OFF_WHH);        // stride 33
    float* biS  = (float*)(smem + OFF_BIH);
    float* bhS  = (float*)(smem + OFF_BHH);
    float* b1S  = (float*)(smem + OFF_B1);
    float* W1T  = (float*)(smem + OFF_W1T);        // [d][cc] = mpW1[cc][d]
    float (*msum)[32] = (float(*)[32])(smem + OFF_MSUM);
    float (*hjpS)[64] = (float(*)[64])(smem + OFF_HJP);
    float (*hS)[32]   = (float(*)[32])(smem + OFF_H);
    float (*msgS)[32] = (float(*)[32])(smem + OFF_MSG);
    float (*giS)[96]  = (float(*)[96])(smem + OFF_GI);
    float (*ghS)[96]  = (float(*)[96])(smem + OFF_GH);

    const int tid  = threadIdx.x;
    const int lane = tid & 63;
    const int wave = tid >> 6;       // 0..7
    const int nsel = wave >> 2;      // node select
    const int nw   = wave & 3;       // wave-within-node
    const int j    = blockIdx.x * 2 + nsel;
    const int q    = lane >> 4;
    const int c    = lane & 15;

    char* m2Lw = smem + OFF_M2L + wave * 2304;     // per-wave 16 edges x 144 B

    // ---------------- prep: tail weights -> LDS (coalesced) ----------------
    for (int n = tid; n < 96 * 64; n += 512)
        WihS[(n >> 6) * 65 + (n & 63)] = p.Wih[n];
    for (int n = tid; n < 96 * 32; n += 512)
        WhhS[(n >> 5) * 33 + (n & 31)] = p.Whh[n];
    if (tid < 96) biS[tid] = p.bih[tid];
    else if (tid < 192) bhS[tid - 96] = p.bhh[tid - 96];
    else if (tid < 256) b1S[tid - 192] = p.mpb1[tid - 192];
    for (int n = tid; n < 64 * 67; n += 512) {
        int cc = n / 67, d = n % 67;
        W1T[d * 64 + cc] = p.mpW1[n];
    }
    __syncthreads();

    // ---------------- prep: h==0 projections, packed f16 -> LLC -----------
    if (tid < 128) {
        int node = tid >> 6, cc = tid & 63;
        int jj = blockIdx.x * 2 + node;
        float bj = p.b[jj];
        hjpS[node][cc] = bj * W1T[66 * 64 + cc] + b1S[cc];
        float si = bj * W1T[65 * 64 + cc];
        float sp = __shfl(si, lane ^ 1);
        if (!(lane & 1))
            atomicExch(&p.hb0[jj * 32 + (cc >> 1)], pkrtz(si, sp));
    }

    // ---------------- persistent per-lane preloads ----------------
    unsigned wj2a[4], wj2b[4];
    #pragma unroll
    for (int i = 0; i < 4; ++i) {
        wj2a[i] = pkrtz(p.mpW1[(q * 8 + 2 * i) * 67 + 64],
                        p.mpW1[(q * 8 + 2 * i + 1) * 67 + 64]);
        wj2b[i] = pkrtz(p.mpW1[(q * 8 + 2 * i + 32) * 67 + 64],
                        p.mpW1[(q * 8 + 2 * i + 33) * 67 + 64]);
    }
    floatx4 b2i[4], b3i[2];
    #pragma unroll
    for (int t4 = 0; t4 < 4; ++t4)
        #pragma unroll
        for (int r = 0; r < 4; ++r) b2i[t4][r] = p.mpb2[t4 * 16 + q * 4 + r];
    #pragma unroll
    for (int t2 = 0; t2 < 2; ++t2)
        #pragma unroll
        for (int r = 0; r < 4; ++r) b3i[t2][r] = p.mpb3[t2 * 16 + q * 4 + r];

    // A-operand weight fragments: Aw2[f][t4][s] = W2[t4*16+c][f*32+q*8+s]
    f16x8 Aw2[2][4], Aw3[2][2];
    #pragma unroll
    for (int f = 0; f < 2; ++f)
        #pragma unroll
        for (int t4 = 0; t4 < 4; ++t4) {
            const float* src = p.mpW2 + (t4 * 16 + c) * 64 + f * 32 + q * 8;
            #pragma unroll
            for (int s = 0; s < 8; ++s) Aw2[f][t4][s] = (_Float16)src[s];
        }
    #pragma unroll
    for (int f = 0; f < 2; ++f)
        #pragma unroll
        for (int t2 = 0; t2 < 2; ++t2) {
            const float* src = p.mpW3 + (t2 * 16 + c) * 64 + f * 32 + q * 8;
            #pragma unroll
            for (int s = 0; s < 8; ++s) Aw3[f][t2][s] = (_Float16)src[s];
        }

    // J values: lane (q=k, c); jA covers groups {8k+nw}, jB {8k+4+nw}
    const float jA = p.J[((8 * q + nw) * 16 + c) * NN + j];
    const float jB = p.J[((8 * q + 4 + nw) * 16 + c) * NN + j];

    xbarrier(p.bar, 1, blockIdx.x);    // hb0 visible everywhere

    // ---------------- 5 message-passing steps ----------------
    for (int t = 0; t < 5; ++t) {
        const unsigned* hb_read = (t & 1) ? p.hb1 : p.hb0;
        unsigned*       hb_next = (t & 1) ? p.hb0 : p.hb1;

        // per-step hjp packed pairs
        unsigned hjp2a[4], hjp2b[4];
        #pragma unroll
        for (int i = 0; i < 4; ++i) {
            hjp2a[i] = pkrtz(hjpS[nsel][q * 8 + 2 * i], hjpS[nsel][q * 8 + 2 * i + 1]);
            hjp2b[i] = pkrtz(hjpS[nsel][q * 8 + 2 * i + 32], hjpS[nsel][q * 8 + 2 * i + 33]);
        }

        float accf[2][4];
        #pragma unroll
        for (int t2 = 0; t2 < 2; ++t2)
            #pragma unroll
            for (int r = 0; r < 4; ++r) accf[t2][r] = 0.0f;

        // staging mapping: thread covers 64 B of row (phase*256 + tid/2)
        const unsigned grow = (unsigned)(tid >> 1);
        const unsigned half = (unsigned)(tid & 1);
        char* ldst = hbS + grow * 144 + half * 64;   // 16-B aligned (144%16==0... base even rows; half*64 keeps 16-B)

        uintx4 cr[4];
        // ---- phase 0: rows 0..255 ----
        {
            const unsigned* gp = hb_read + grow * 32 + half * 16;
            #pragma unroll
            for (int i = 0; i < 4; ++i) issue16(gp + i * 4, cr[i]);
            waitall4(cr[0], cr[1], cr[2], cr[3]);
            #pragma unroll
            for (int i = 0; i < 4; ++i) *(uintx4*)(ldst + i * 16) = cr[i];
        }
        __syncthreads();
        // issue phase-1 loads; they fly during k=0,1 compute
        {
            const unsigned* gp = hb_read + (256 + grow) * 32 + half * 16;
            #pragma unroll
            for (int i = 0; i < 4; ++i) issue16(gp + i * 4, cr[i]);
        }

        // ---- edge group (swapped MFMA, packed f16); Glocal in 0..15 ----
        auto edge_group = [&](int Glocal, float Jv) {
            const char* rb = hbS + (Glocal * 16 + c) * 144;
            uintx4 vlo = *(const uintx4*)(rb + q * 16);
            uintx4 vhi = *(const uintx4*)(rb + 64 + q * 16);
            const unsigned Jp = pkrtz(Jv, Jv);

            uintx4 a0u, a1u;
            #pragma unroll
            for (int i = 0; i < 4; ++i) {
                a0u[i] = pk_relu(pk_fma(Jp, wj2a[i], pk_add(vlo[i], hjp2a[i])));
                a1u[i] = pk_relu(pk_fma(Jp, wj2b[i], pk_add(vhi[i], hjp2b[i])));
            }
            f16x8 B0 = __builtin_bit_cast(f16x8, a0u);
            f16x8 B1 = __builtin_bit_cast(f16x8, a1u);

            floatx4 c1[4];
            #pragma unroll
            for (int t4 = 0; t4 < 4; ++t4) {
                c1[t4] = __builtin_amdgcn_mfma_f32_16x16x32_f16(Aw2[0][t4], B0, b2i[t4], 0, 0, 0);
                c1[t4] = __builtin_amdgcn_mfma_f32_16x16x32_f16(Aw2[1][t4], B1, c1[t4], 0, 0, 0);
            }
            #pragma unroll
            for (int t4 = 0; t4 < 4; ++t4) {
                unsigned p0 = pkrtz(fmaxf(c1[t4][0], 0.f), fmaxf(c1[t4][1], 0.f));
                unsigned p1 = pkrtz(fmaxf(c1[t4][2], 0.f), fmaxf(c1[t4][3], 0.f));
                *(uint2*)(m2Lw + c * 144 + t4 * 32 + q * 8) = make_uint2(p0, p1);
            }
            uintx4 rlo = *(const uintx4*)(m2Lw + c * 144 + q * 16);
            uintx4 rhi = *(const uintx4*)(m2Lw + c * 144 + 64 + q * 16);
            f16x8 B2lo = __builtin_bit_cast(f16x8, rlo);
            f16x8 B2hi = __builtin_bit_cast(f16x8, rhi);

            floatx4 c2[2];
            #pragma unroll
            for (int t2 = 0; t2 < 2; ++t2) {
                c2[t2] = __builtin_amdgcn_mfma_f32_16x16x32_f16(Aw3[0][t2], B2lo, b3i[t2], 0, 0, 0);
                c2[t2] = __builtin_amdgcn_mfma_f32_16x16x32_f16(Aw3[1][t2], B2hi, c2[t2], 0, 0, 0);
            }
            #pragma unroll
            for (int t2 = 0; t2 < 2; ++t2)
                #pragma unroll
                for (int r = 0; r < 4; ++r)
                    accf[t2][r] += fmaxf(c2[t2][r], 0.0f);
        };

        // k=0,1 on phase-0 rows: groups {nw,4+nw,8+nw,12+nw} (local = global)
        edge_group(nw,      __shfl(jA, 0 * 16 + c));
        edge_group(4 + nw,  __shfl(jB, 0 * 16 + c));
        edge_group(8 + nw,  __shfl(jA, 1 * 16 + c));
        edge_group(12 + nw, __shfl(jB, 1 * 16 + c));
        __syncthreads();   // all phase-0 hbS reads complete
        {
            waitall4(cr[0], cr[1], cr[2], cr[3]);
            #pragma unroll
            for (int i = 0; i < 4; ++i) *(uintx4*)(ldst + i * 16) = cr[i];
        }
        __syncthreads();   // phase-1 staged
        // k=2,3 on phase-1 rows: groups 16..31, local = G-16
        edge_group(nw,      __shfl(jA, 2 * 16 + c));
        edge_group(4 + nw,  __shfl(jB, 2 * 16 + c));
        edge_group(8 + nw,  __shfl(jA, 3 * 16 + c));
        edge_group(12 + nw, __shfl(jB, 3 * 16 + c));

        // column sums: butterfly over edge lanes c
        #pragma unroll
        for (int m = 1; m < 16; m <<= 1)
            #pragma unroll
            for (int t2 = 0; t2 < 2; ++t2)
                #pragma unroll
                for (int r = 0; r < 4; ++r)
                    accf[t2][r] += __shfl_xor(accf[t2][r], m);
        if (c == 0) {
            #pragma unroll
            for (int t2 = 0; t2 < 2; ++t2)
                #pragma unroll
                for (int r = 0; r < 4; ++r)
                    msum[wave][t2 * 16 + q * 4 + r] = accf[t2][r];
        }
        __syncthreads();

        // ---- block-local tail (LDS weights) ----
        if (tid < 64) {
            int node = tid >> 5, d = tid & 31;
            msgS[node][d] = msum[node * 4 + 0][d] + msum[node * 4 + 1][d] +
                            msum[node * 4 + 2][d] + msum[node * 4 + 3][d];
        }
        __syncthreads();

        if (tid < 192) {
            int node = tid / 96, r = tid % 96;
            int g = r >> 5, d = r & 31;
            const float* wi = WihS + (g * 32 + d) * 65;
            const float* wh = WhhS + (g * 32 + d) * 33;
            float a  = biS[g * 32 + d];
            float bb = bhS[g * 32 + d];
            if (t > 0) {
                #pragma unroll
                for (int k = 0; k < 32; ++k) {
                    float hv = hS[node][k];
                    a  = fmaf(hv, wi[k], a);
                    bb = fmaf(hv, wh[k], bb);
                }
            }
            #pragma unroll
            for (int k = 0; k < 32; ++k) a = fmaf(msgS[node][k], wi[32 + k], a);
            giS[node][r] = a; ghS[node][r] = bb;
        }
        __syncthreads();

        if (tid < 64) {
            int node = tid >> 5, d = tid & 31;
            float r  = sigmoidf_(giS[node][d] + ghS[node][d]);
            float z  = sigmoidf_(giS[node][32 + d] + ghS[node][32 + d]);
            float ng = tanhf(giS[node][64 + d] + r * ghS[node][64 + d]);
            float hold = (t > 0) ? hS[node][d] : 0.0f;
            hS[node][d] = (1.0f - z) * ng + z * hold;
        }
        __syncthreads();

        if (t < 4) {
            if (tid < 128) {   // projections via W1T (lane-stride-1 LDS reads)
                int node = tid >> 6, cc = tid & 63;
                int jj = blockIdx.x * 2 + node;
                float bj = p.b[jj];
                float si = bj * W1T[65 * 64 + cc];
                float sj = bj * W1T[66 * 64 + cc] + b1S[cc];
                #pragma unroll
                for (int d = 0; d < 32; ++d) {
                    float hv = hS[node][d];
                    si = fmaf(hv, W1T[d * 64 + cc], si);
                    sj = fmaf(hv, W1T[(32 + d) * 64 + cc], sj);
                }
                hjpS[node][cc] = sj;
                float sp = __shfl(si, lane ^ 1);
                if (!(lane & 1))
                    atomicExch(&hb_next[jj * 32 + (cc >> 1)], pkrtz(si, sp));
            }
            xbarrier(p.bar, (unsigned)(t + 2), blockIdx.x);
        } else {
            if (wave < 2) {   // readout (runs once; global weights fine)
                int node = wave;
                int jj = blockIdx.x * 2 + node;
                float y1 = p.rb1[lane];
                #pragma unroll
                for (int k = 0; k < 32; ++k) y1 = fmaf(hS[node][k], p.rW1[lane * 32 + k], y1);
                y1 = fmaxf(y1, 0.0f);
                float y2 = p.rb2[lane];
                #pragma unroll
                for (int k = 0; k < 64; ++k) y2 = fmaf(__shfl(y1, k), p.rW2[lane * 64 + k], y2);
                y2 = fmaxf(y2, 0.0f);
                float y3 = (lane < 2) ? p.rb3[lane] : 0.0f;
                #pragma unroll
                for (int k = 0; k < 64; ++k) {
                    float v = __shfl(y2, k);
                    if (lane < 2) y3 = fmaf(v, p.rW3[lane * 64 + k], y3);
                }
                if (lane < 2) p.out[jj * 2 + lane] = sigmoidf_(y3);
            }
        }
    }
}

// ---------------------------------------------------------------------------
extern "C" void kernel_launch(void* const* d_in, const int* in_sizes, int n_in,
                              void* d_out, int out_size, void* d_ws, size_t ws_size,
                              hipStream_t stream)
{
    float* ws = (float*)d_ws;

    KParams p;
    p.J    = (const float*)d_in[0];
    p.b    = (const float*)d_in[1];
    p.mpW1 = (const float*)d_in[2];
    p.mpb1 = (const float*)d_in[3];
    p.mpW2 = (const float*)d_in[4];
    p.mpb2 = (const float*)d_in[5];
    p.mpW3 = (const float*)d_in[6];
    p.mpb3 = (const float*)d_in[7];
    p.Wih  = (const float*)d_in[8];
    p.Whh  = (const float*)d_in[9];
    p.bih  = (const float*)d_in[10];
    p.bhh  = (const float*)d_in[11];
    p.rW1  = (const float*)d_in[12];
    p.rb1  = (const float*)d_in[13];
    p.rW2  = (const float*)d_in[14];
    p.rb2  = (const float*)d_in[15];
    p.rW3  = (const float*)d_in[16];
    p.rb3  = (const float*)d_in[17];
    p.out  = (float*)d_out;

    p.hb0  = (unsigned*)ws;            // 512*32 u32 (packed f16 pairs)
    p.hb1  = (unsigned*)(ws + 16384);
    p.bar  = (unsigned*)(ws + 32768);  // tree barrier state (<=4KB)

    (void)hipMemsetAsync(p.bar, 0, 4096, stream);

    (void)hipFuncSetAttribute((const void*)fused_kernel,
                              hipFuncAttributeMaxDynamicSharedMemorySize, LDS_TOTAL);
    fused_kernel<<<dim3(NB), dim3(512), LDS_TOTAL, stream>>>(p);
}

// Round 14
// 151.378 us; speedup vs baseline: 1.8940x; 1.1653x over previous
//
#include <hip/hip_runtime.h>
#include <math.h>

#define NN 512
#define SD 32
#define HM 64

typedef _Float16 f16x8 __attribute__((ext_vector_type(8)));
typedef float floatx4 __attribute__((ext_vector_type(4)));
typedef unsigned uintx4 __attribute__((ext_vector_type(4)));

// ---- step-kernel dynamic LDS layout (bytes) ----
#define OFF_HBS   0        // 512 rows x 144 B packed-f16 hip        = 73728
#define OFF_M2L   73728    // 8 waves x 2304 B                       = 18432
#define OFF_MSUM  92160    // 8x32 f32
#define OFF_HPREV 93184    // 2x32 f32
#define OFF_HS    93440    // 2x32 f32
#define OFF_MSG   93696    // 2x32 f32
#define OFF_GI    93952    // 2x96 f32
#define OFF_GH    94720    // 2x96 f32
#define LDS_TOTAL 95488

__device__ __forceinline__ float sigmoidf_(float x) {
    return 1.0f / (1.0f + __expf(-x));
}
__device__ __forceinline__ unsigned pkrtz(float a, float b) {
    unsigned r;
    asm("v_cvt_pkrtz_f16_f32 %0, %1, %2" : "=v"(r) : "v"(a), "v"(b));
    return r;
}
__device__ __forceinline__ unsigned pk_add(unsigned a, unsigned b) {
    unsigned r;
    asm("v_pk_add_f16 %0, %1, %2" : "=v"(r) : "v"(a), "v"(b));
    return r;
}
__device__ __forceinline__ unsigned pk_fma(unsigned a, unsigned b, unsigned c) {
    unsigned r;
    asm("v_pk_fma_f16 %0, %1, %2, %3" : "=v"(r) : "v"(a), "v"(b), "v"(c));
    return r;
}
__device__ __forceinline__ unsigned pk_relu(unsigned a) {
    unsigned r, z = 0u;
    asm("v_pk_max_f16 %0, %1, %2" : "=v"(r) : "v"(a), "v"(z));
    return r;
}

// ---------------------------------------------------------------------------
struct PParams {
    const float *J, *b, *mpW1, *mpb1, *mpW2, *mpW3, *Wih, *Whh, *rW1, *rW2;
    float *JT, *W1T, *WihT, *WhhT, *rW1T, *rW2T;
    unsigned *w2p, *w3p, *wjp, *hb0, *hjp0;
};

// Prep: JT transpose, weight transposes, MFMA-fragment prepack (per-lane
// contiguous 16 B), h==0 projections. 256 blocks x 256 threads.
__global__ __launch_bounds__(256) void prep_kernel(PParams pp)
{
    __shared__ float tile[32][33];
    const int tid = threadIdx.x;
    const int b   = blockIdx.x;
    {   // JT: 16x16 grid of 32x32 tiles
        int bx = b & 15, by = b >> 4;
        int tx = tid & 31, ty = tid >> 5;
        #pragma unroll
        for (int r = 0; r < 32; r += 8)
            tile[ty + r][tx] = pp.J[(by * 32 + ty + r) * NN + bx * 32 + tx];
        __syncthreads();
        #pragma unroll
        for (int r = 0; r < 32; r += 8)
            pp.JT[(bx * 32 + ty + r) * NN + by * 32 + tx] = tile[tx][ty + r];
    }
    if (b == 0 && tid < 64) {
        int l = tid, qq = l >> 4, cc = l & 15;
        for (int f = 0; f < 2; ++f)
            for (int t4 = 0; t4 < 4; ++t4) {
                const float* src = pp.mpW2 + (t4 * 16 + cc) * 64 + f * 32 + qq * 8;
                unsigned* dst = pp.w2p + ((f * 4 + t4) * 64 + l) * 4;
                for (int i = 0; i < 4; ++i) dst[i] = pkrtz(src[2 * i], src[2 * i + 1]);
            }
        for (int f = 0; f < 2; ++f)
            for (int t2 = 0; t2 < 2; ++t2) {
                const float* src = pp.mpW3 + (t2 * 16 + cc) * 64 + f * 32 + qq * 8;
                unsigned* dst = pp.w3p + ((f * 2 + t2) * 64 + l) * 4;
                for (int i = 0; i < 4; ++i) dst[i] = pkrtz(src[2 * i], src[2 * i + 1]);
            }
        for (int s = 0; s < 2; ++s) {
            unsigned* dst = pp.wjp + (s * 64 + l) * 4;
            for (int i = 0; i < 4; ++i) {
                int r0 = qq * 8 + 2 * i + s * 32;
                dst[i] = pkrtz(pp.mpW1[r0 * 67 + 64], pp.mpW1[(r0 + 1) * 67 + 64]);
            }
        }
    }
    if (b == 1)
        for (int n = tid; n < 64 * 67; n += 256) {
            int cc = n / 67, d = n % 67;
            pp.W1T[d * 64 + cc] = pp.mpW1[n];
        }
    if (b == 2)
        for (int n = tid; n < 96 * 64; n += 256)
            pp.WihT[(n & 63) * 96 + (n >> 6)] = pp.Wih[n];
    if (b == 3)
        for (int n = tid; n < 96 * 32; n += 256)
            pp.WhhT[(n & 31) * 96 + (n >> 5)] = pp.Whh[n];
    if (b == 4) {
        for (int n = tid; n < 64 * 32; n += 256)
            pp.rW1T[(n & 31) * 64 + (n >> 5)] = pp.rW1[n];
        for (int n = tid; n < 64 * 64; n += 256)
            pp.rW2T[(n & 63) * 64 + (n >> 6)] = pp.rW2[n];
    }
    if (b >= 16 && b < 144) {
        int jj = (b - 16) * 4 + (tid >> 6);
        int cc = tid & 63;
        float bj = pp.b[jj];
        float sj = bj * pp.mpW1[cc * 67 + 66] + pp.mpb1[cc];
        float si = bj * pp.mpW1[cc * 67 + 65];
        float sjp = __shfl(sj, cc ^ 1);
        float sip = __shfl(si, cc ^ 1);
        if (!(cc & 1)) {
            pp.hjp0[jj * 32 + (cc >> 1)] = pkrtz(sj, sjp);
            pp.hb0[jj * 32 + (cc >> 1)]  = pkrtz(si, sip);
        }
    }
}

// ---------------------------------------------------------------------------
struct SParams {
    const unsigned *hbR;  unsigned *hbW;
    const unsigned *hjR;  unsigned *hjW;
    const float *hR;      float *hW;
    const float *JT, *W1T, *WihT, *WhhT, *bih, *bhh, *mpb2, *mpb3, *b, *mpb1;
    const float *rW1T, *rW2T, *rW3, *rb1, *rb2, *rb3;
    const unsigned *w2p, *w3p, *wjp;
    float *out;
    int hzero, rdout;
};

// One message-passing step. 256 blocks x 512 threads; block owns nodes
// 2*bid, 2*bid+1. Cross-dispatch coherence via stream ordering (normal
// cached loads/stores) — no barriers, no cache-bypass.
__global__ __launch_bounds__(512, 1) void step_kernel(SParams s)
{
    extern __shared__ __align__(16) char smem[];
    char* hbS = smem + OFF_HBS;
    float (*msum)[32]   = (float(*)[32])(smem + OFF_MSUM);
    float (*hPrevS)[32] = (float(*)[32])(smem + OFF_HPREV);
    float (*hS)[32]     = (float(*)[32])(smem + OFF_HS);
    float (*msgS)[32]   = (float(*)[32])(smem + OFF_MSG);
    float (*giS)[96]    = (float(*)[96])(smem + OFF_GI);
    float (*ghS)[96]    = (float(*)[96])(smem + OFF_GH);

    const int tid  = threadIdx.x;
    const int lane = tid & 63;
    const int wave = tid >> 6;
    const int nsel = wave >> 2;
    const int nw   = wave & 3;
    const int j    = blockIdx.x * 2 + nsel;
    const int q    = lane >> 4;
    const int c    = lane & 15;
    char* m2Lw = smem + OFF_M2L + wave * 2304;

    // ---- stage hb (64 KB) -> LDS ----
    {
        uintx4 cr[8];
        const uintx4* gp = (const uintx4*)s.hbR;
        #pragma unroll
        for (int k = 0; k < 8; ++k) cr[k] = gp[k * 512 + tid];
        #pragma unroll
        for (int k = 0; k < 8; ++k) {
            int row = k * 64 + (tid >> 3);
            *(uintx4*)(hbS + row * 144 + (tid & 7) * 16) = cr[k];
        }
    }
    if (tid < 64 && !s.hzero)
        hPrevS[tid >> 5][tid & 31] = s.hR[blockIdx.x * 64 + tid];
    __syncthreads();

    // ---- per-lane preloads (coalesced, L2) ----
    f16x8 Aw2[2][4], Aw3[2][2];
    #pragma unroll
    for (int f = 0; f < 2; ++f)
        #pragma unroll
        for (int t4 = 0; t4 < 4; ++t4)
            Aw2[f][t4] = __builtin_bit_cast(f16x8,
                ((const uintx4*)s.w2p)[(f * 4 + t4) * 64 + lane]);
    #pragma unroll
    for (int f = 0; f < 2; ++f)
        #pragma unroll
        for (int t2 = 0; t2 < 2; ++t2)
            Aw3[f][t2] = __builtin_bit_cast(f16x8,
                ((const uintx4*)s.w3p)[(f * 2 + t2) * 64 + lane]);
    uintx4 wja = ((const uintx4*)s.wjp)[lane];
    uintx4 wjb = ((const uintx4*)s.wjp)[64 + lane];
    uintx4 hja = ((const uintx4*)s.hjR)[j * 8 + q];
    uintx4 hjb = ((const uintx4*)s.hjR)[j * 8 + 4 + q];

    floatx4 b2i[4], b3i[2];
    #pragma unroll
    for (int t4 = 0; t4 < 4; ++t4)
        #pragma unroll
        for (int r = 0; r < 4; ++r) b2i[t4][r] = s.mpb2[t4 * 16 + q * 4 + r];
    #pragma unroll
    for (int t2 = 0; t2 < 2; ++t2)
        #pragma unroll
        for (int r = 0; r < 4; ++r) b3i[t2][r] = s.mpb3[t2 * 16 + q * 4 + r];

    const float jA = s.JT[j * NN + (8 * q + nw) * 16 + c];
    const float jB = s.JT[j * NN + (8 * q + 4 + nw) * 16 + c];

    float accf[2][4];
    #pragma unroll
    for (int t2 = 0; t2 < 2; ++t2)
        #pragma unroll
        for (int r = 0; r < 4; ++r) accf[t2][r] = 0.0f;

    auto edge_group = [&](int G, float Jv) {
        const char* rb = hbS + (G * 16 + c) * 144;
        uintx4 vlo = *(const uintx4*)(rb + q * 16);
        uintx4 vhi = *(const uintx4*)(rb + 64 + q * 16);
        const unsigned Jp = pkrtz(Jv, Jv);

        uintx4 a0u, a1u;
        #pragma unroll
        for (int i = 0; i < 4; ++i) {
            a0u[i] = pk_relu(pk_fma(Jp, wja[i], pk_add(vlo[i], hja[i])));
            a1u[i] = pk_relu(pk_fma(Jp, wjb[i], pk_add(vhi[i], hjb[i])));
        }
        f16x8 B0 = __builtin_bit_cast(f16x8, a0u);
        f16x8 B1 = __builtin_bit_cast(f16x8, a1u);

        floatx4 c1[4];
        #pragma unroll
        for (int t4 = 0; t4 < 4; ++t4) {
            c1[t4] = __builtin_amdgcn_mfma_f32_16x16x32_f16(Aw2[0][t4], B0, b2i[t4], 0, 0, 0);
            c1[t4] = __builtin_amdgcn_mfma_f32_16x16x32_f16(Aw2[1][t4], B1, c1[t4], 0, 0, 0);
        }
        #pragma unroll
        for (int t4 = 0; t4 < 4; ++t4) {
            unsigned p0 = pkrtz(fmaxf(c1[t4][0], 0.f), fmaxf(c1[t4][1], 0.f));
            unsigned p1 = pkrtz(fmaxf(c1[t4][2], 0.f), fmaxf(c1[t4][3], 0.f));
            *(uint2*)(m2Lw + c * 144 + t4 * 32 + q * 8) = make_uint2(p0, p1);
        }
        uintx4 rlo = *(const uintx4*)(m2Lw + c * 144 + q * 16);
        uintx4 rhi = *(const uintx4*)(m2Lw + c * 144 + 64 + q * 16);
        f16x8 B2lo = __builtin_bit_cast(f16x8, rlo);
        f16x8 B2hi = __builtin_bit_cast(f16x8, rhi);

        floatx4 c2[2];
        #pragma unroll
        for (int t2 = 0; t2 < 2; ++t2) {
            c2[t2] = __builtin_amdgcn_mfma_f32_16x16x32_f16(Aw3[0][t2], B2lo, b3i[t2], 0, 0, 0);
            c2[t2] = __builtin_amdgcn_mfma_f32_16x16x32_f16(Aw3[1][t2], B2hi, c2[t2], 0, 0, 0);
        }
        #pragma unroll
        for (int t2 = 0; t2 < 2; ++t2)
            #pragma unroll
            for (int r = 0; r < 4; ++r)
                accf[t2][r] += fmaxf(c2[t2][r], 0.0f);
    };

    #pragma unroll
    for (int k = 0; k < 4; ++k) {
        edge_group(8 * k + nw,     __shfl(jA, k * 16 + c));
        edge_group(8 * k + 4 + nw, __shfl(jB, k * 16 + c));
    }

    #pragma unroll
    for (int m = 1; m < 16; m <<= 1)
        #pragma unroll
        for (int t2 = 0; t2 < 2; ++t2)
            #pragma unroll
            for (int r = 0; r < 4; ++r)
                accf[t2][r] += __shfl_xor(accf[t2][r], m);
    if (c == 0) {
        #pragma unroll
        for (int t2 = 0; t2 < 2; ++t2)
            #pragma unroll
            for (int r = 0; r < 4; ++r)
                msum[wave][t2 * 16 + q * 4 + r] = accf[t2][r];
    }
    __syncthreads();

    if (tid < 64) {
        int node = tid >> 5, d = tid & 31;
        msgS[node][d] = msum[node * 4 + 0][d] + msum[node * 4 + 1][d] +
                        msum[node * 4 + 2][d] + msum[node * 4 + 3][d];
    }
    __syncthreads();

    if (tid < 192) {
        int node = tid / 96, r = tid % 96;
        float a  = s.bih[r];
        float bb = s.bhh[r];
        if (!s.hzero) {
            #pragma unroll
            for (int k = 0; k < 32; ++k) {
                float hv = hPrevS[node][k];
                a  = fmaf(hv, s.WihT[k * 96 + r], a);
                bb = fmaf(hv, s.WhhT[k * 96 + r], bb);
            }
        }
        #pragma unroll
        for (int k = 0; k < 32; ++k)
            a = fmaf(msgS[node][k], s.WihT[(32 + k) * 96 + r], a);
        giS[node][r] = a; ghS[node][r] = bb;
    }
    __syncthreads();

    if (tid < 64) {
        int node = tid >> 5, d = tid & 31;
        float r  = sigmoidf_(giS[node][d] + ghS[node][d]);
        float z  = sigmoidf_(giS[node][32 + d] + ghS[node][32 + d]);
        float ng = tanhf(giS[node][64 + d] + r * ghS[node][64 + d]);
        float hold = s.hzero ? 0.0f : hPrevS[node][d];
        float hv = (1.0f - z) * ng + z * hold;
        hS[node][d] = hv;
        s.hW[blockIdx.x * 64 + tid] = hv;
    }
    __syncthreads();

    if (!s.rdout) {
        if (tid < 128) {
            int node = tid >> 6, cc = tid & 63;
            int jj = blockIdx.x * 2 + node;
            float bj = s.b[jj];
            float si = bj * s.W1T[65 * 64 + cc];
            float sj = bj * s.W1T[66 * 64 + cc] + s.mpb1[cc];
            #pragma unroll
            for (int d = 0; d < 32; ++d) {
                float hv = hS[node][d];
                si = fmaf(hv, s.W1T[d * 64 + cc], si);
                sj = fmaf(hv, s.W1T[(32 + d) * 64 + cc], sj);
            }
            float sip = __shfl(si, lane ^ 1);
            float sjp = __shfl(sj, lane ^ 1);
            if (!(cc & 1)) {
                s.hbW[jj * 32 + (cc >> 1)] = pkrtz(si, sip);
                s.hjW[jj * 32 + (cc >> 1)] = pkrtz(sj, sjp);
            }
        }
    } else {
        if (wave < 2) {
            int node = wave;
            int jj = blockIdx.x * 2 + node;
            float y1 = s.rb1[lane];
            #pragma unroll
            for (int k = 0; k < 32; ++k)
                y1 = fmaf(hS[node][k], s.rW1T[k * 64 + lane], y1);
            y1 = fmaxf(y1, 0.0f);
            float y2 = s.rb2[lane];
            #pragma unroll
            for (int k = 0; k < 64; ++k)
                y2 = fmaf(__shfl(y1, k), s.rW2T[k * 64 + lane], y2);
            y2 = fmaxf(y2, 0.0f);
            float y3 = (lane < 2) ? s.rb3[lane] : 0.0f;
            #pragma unroll
            for (int k = 0; k < 64; ++k) {
                float v = __shfl(y2, k);
                if (lane < 2) y3 = fmaf(v, s.rW3[lane * 64 + k], y3);
            }
            if (lane < 2) s.out[jj * 2 + lane] = sigmoidf_(y3);
        }
    }
}

// ---------------------------------------------------------------------------
extern "C" void kernel_launch(void* const* d_in, const int* in_sizes, int n_in,
                              void* d_out, int out_size, void* d_ws, size_t ws_size,
                              hipStream_t stream)
{
    float* ws = (float*)d_ws;

    const float* J    = (const float*)d_in[0];
    const float* b    = (const float*)d_in[1];
    const float* mpW1 = (const float*)d_in[2];
    const float* mpb1 = (const float*)d_in[3];
    const float* mpW2 = (const float*)d_in[4];
    const float* mpb2 = (const float*)d_in[5];
    const float* mpW3 = (const float*)d_in[6];
    const float* mpb3 = (const float*)d_in[7];
    const float* Wih  = (const float*)d_in[8];
    const float* Whh  = (const float*)d_in[9];
    const float* bih  = (const float*)d_in[10];
    const float* bhh  = (const float*)d_in[11];
    const float* rW1  = (const float*)d_in[12];
    const float* rb1  = (const float*)d_in[13];
    const float* rW2  = (const float*)d_in[14];
    const float* rb2  = (const float*)d_in[15];
    const float* rW3  = (const float*)d_in[16];
    const float* rb3  = (const float*)d_in[17];

    float*    JT   = ws;                       // 262144
    float*    W1T  = ws + 262144;              // 4288
    float*    WihT = ws + 266432;              // 6144
    float*    WhhT = ws + 272576;              // 3072
    float*    rW1T = ws + 275648;              // 2048
    float*    rW2T = ws + 277696;              // 4096
    unsigned* w2p  = (unsigned*)(ws + 281792); // 2048
    unsigned* w3p  = (unsigned*)(ws + 283840); // 1024
    unsigned* wjp  = (unsigned*)(ws + 284864); // 512
    unsigned* hb0  = (unsigned*)(ws + 285376); // 16384
    unsigned* hb1  = (unsigned*)(ws + 301760); // 16384
    unsigned* hj0  = (unsigned*)(ws + 318144); // 16384
    unsigned* hj1  = (unsigned*)(ws + 334528); // 16384
    float*    h0   = ws + 350912;              // 16384
    float*    h1   = ws + 367296;              // 16384

    PParams pp;
    pp.J = J; pp.b = b; pp.mpW1 = mpW1; pp.mpb1 = mpb1; pp.mpW2 = mpW2;
    pp.mpW3 = mpW3; pp.Wih = Wih; pp.Whh = Whh; pp.rW1 = rW1; pp.rW2 = rW2;
    pp.JT = JT; pp.W1T = W1T; pp.WihT = WihT; pp.WhhT = WhhT;
    pp.rW1T = rW1T; pp.rW2T = rW2T;
    pp.w2p = w2p; pp.w3p = w3p; pp.wjp = wjp; pp.hb0 = hb0; pp.hjp0 = hj0;

    (void)hipFuncSetAttribute((const void*)step_kernel,
                              hipFuncAttributeMaxDynamicSharedMemorySize, LDS_TOTAL);

    prep_kernel<<<dim3(256), dim3(256), 0, stream>>>(pp);

    SParams s;
    s.JT = JT; s.W1T = W1T; s.WihT = WihT; s.WhhT = WhhT;
    s.bih = bih; s.bhh = bhh; s.mpb2 = mpb2; s.mpb3 = mpb3; s.b = b; s.mpb1 = mpb1;
    s.rW1T = rW1T; s.rW2T = rW2T; s.rW3 = rW3; s.rb1 = rb1; s.rb2 = rb2; s.rb3 = rb3;
    s.w2p = w2p; s.w3p = w3p; s.wjp = wjp;
    s.out = (float*)d_out;

    for (int t = 0; t < 5; ++t) {
        s.hbR = (t & 1) ? hb1 : hb0;
        s.hbW = (t & 1) ? hb0 : hb1;
        s.hjR = (t & 1) ? hj1 : hj0;
        s.hjW = (t & 1) ? hj0 : hj1;
        s.hR  = (t & 1) ? h0 : h1;
        s.hW  = (t & 1) ? h1 : h0;
        s.hzero = (t == 0);
        s.rdout = (t == 4);
        step_kernel<<<dim3(256), dim3(512), LDS_TOTAL, stream>>>(s);
    }
}